// Round 16
// baseline (353.727 us; speedup 1.0000x reference)
//
#include <hip/hip_runtime.h>

#define NUSERS  200000
#define NMOVIES 200000
#define NROWS   200000
#define NCB     782            // coarse bins: key >> 8
#define NB      512            // partition chunks per stream
#define CAPB    1792           // csr capacity per bin
#define ELCAP   1792
#define OVF_MAX 8192

typedef __attribute__((ext_vector_type(8))) short bf16x8;
typedef __attribute__((ext_vector_type(4))) float f32x4;

// ---------------------------------------------------------------------------
// Fast block-wide inclusive scan over 256 threads: wave-level shfl scan +
// 4-word cross-wave combine. 2 barriers (vs 16 for Hillis-Steele in LDS).
// wsum must be a __shared__ int[4].
// ---------------------------------------------------------------------------
__device__ __forceinline__ int block_scan_incl(int v, int tid, int* wsum)
{
#pragma unroll
    for (int off = 1; off < 64; off <<= 1) {
        const int t = __shfl_up(v, off);
        if ((tid & 63) >= off) v += t;
    }
    const int wv = tid >> 6;
    if ((tid & 63) == 63) wsum[wv] = v;
    __syncthreads();
    int add = 0;
    if (wv > 0) add += wsum[0];
    if (wv > 1) add += wsum[1];
    if (wv > 2) add += wsum[2];
    __syncthreads();           // allow wsum reuse by a subsequent scan
    return v + add;
}

// ---------------------------------------------------------------------------
// K1: atomic-free partition. Block (s,blk) bins its chunk by key>>8 in LDS
// and writes it back bin-major + C (counts) + LB (offsets).
// Streams: 0 = um user-side (key=a,val=b); 1 = um movie-side (key=b,val=a);
//          2 = me (key=d, val=s).  part entries: (val<<8)|(key&255).
// ---------------------------------------------------------------------------
__global__ __launch_bounds__(256) void bin_scatter_kernel(
    const int* __restrict__ um, const int* __restrict__ me,
    int* __restrict__ C, int* __restrict__ LB, int* __restrict__ part,
    int E_um, int E_me, int CH_um, int CH_me)
{
    __shared__ int hist[NCB];
    __shared__ int lscan[NCB];
    __shared__ int wsum[4];
    __shared__ int stage[1984];

    const int bid = blockIdx.x;
    const int s = bid / NB;
    const int blk = bid % NB;
    const int E  = (s < 2) ? E_um : E_me;
    const int CH = (s < 2) ? CH_um : CH_me;
    const int t0 = blk * CH;
    const int n = max(0, min(t0 + CH, E) - t0);
    const int tid = threadIdx.x;

    const int* kp;
    const int* vp;
    if (s == 0)      { kp = um;        vp = um + E_um; }
    else if (s == 1) { kp = um + E_um; vp = um; }
    else             { kp = me + E_me; vp = me; }

    for (int i = tid; i < NCB; i += 256) hist[i] = 0;
    __syncthreads();

    for (int j = tid; j < n; j += 256) {
        const int key = kp[t0 + j];
        atomicAdd(&hist[key >> 8], 1);
    }
    __syncthreads();

    const int crow = (s * NB + blk) * NCB;
    for (int i = tid; i < NCB; i += 256) C[crow + i] = hist[i];

    {
        const int b4 = tid * 4;
        const int v0 = (b4 + 0 < NCB) ? hist[b4 + 0] : 0;
        const int v1 = (b4 + 1 < NCB) ? hist[b4 + 1] : 0;
        const int v2 = (b4 + 2 < NCB) ? hist[b4 + 2] : 0;
        const int v3 = (b4 + 3 < NCB) ? hist[b4 + 3] : 0;
        const int ssum = v0 + v1 + v2 + v3;
        const int incl = block_scan_incl(ssum, tid, wsum);
        const int excl = incl - ssum;
        if (b4 + 0 < NCB) lscan[b4 + 0] = excl;
        if (b4 + 1 < NCB) lscan[b4 + 1] = excl + v0;
        if (b4 + 2 < NCB) lscan[b4 + 2] = excl + v0 + v1;
        if (b4 + 3 < NCB) lscan[b4 + 3] = excl + v0 + v1 + v2;
    }
    __syncthreads();

    for (int i = tid; i < NCB; i += 256) LB[crow + i] = lscan[i];
    for (int i = tid; i < NCB; i += 256) hist[i] = lscan[i];
    __syncthreads();

    for (int j = tid; j < n; j += 256) {
        const int key = kp[t0 + j];
        const int val = vp[t0 + j];
        const int pos = atomicAdd(&hist[key >> 8], 1);
        stage[pos] = (val << 8) | (key & 255);
    }
    __syncthreads();

    int* preg;
    if (s == 0)      preg = part + (size_t)blk * CH_um;
    else if (s == 1) preg = part + (size_t)NB * CH_um + (size_t)blk * CH_um;
    else             preg = part + (size_t)2 * NB * CH_um + (size_t)blk * CH_me;
    for (int i = tid; i < n; i += 256) preg[i] = stage[i];
}

// ---------------------------------------------------------------------------
// K2: per-bin CSR builder. Copies the bin's edges from the NB fragments into
// LDS (thread-per-fragment), fine-sorts by dst&255 via LDS hist+scan+rank,
// flushes a contiguous src list + exact rowcnt/rowstart.
// ---------------------------------------------------------------------------
__global__ __launch_bounds__(256) void bin_csr_kernel(
    const int* __restrict__ part,
    const int* __restrict__ C, const int* __restrict__ LB,
    int* __restrict__ csr,            // [3][NCB][CAPB]
    int* __restrict__ rowcnt_all,     // [3][NROWS]
    int* __restrict__ rowstart_all,   // [3][NROWS]
    int* __restrict__ ovf_meta, int* __restrict__ ovf_list,
    int CH_um, int CH_me)
{
    __shared__ int cfrag[NB];
    __shared__ int foff[NB + 1];
    __shared__ int wsum[4];
    __shared__ int el[ELCAP];
    __shared__ int sorted[ELCAP];
    __shared__ int fhist[256];
    __shared__ int frank[256];

    const int bid = blockIdx.x;
    const int s = bid / NCB;
    const int bin = bid % NCB;
    const int tid = threadIdx.x;
    const int CH = (s < 2) ? CH_um : CH_me;
    const int* preg = part + (s == 0 ? (size_t)0
                      : (s == 1 ? (size_t)NB * CH_um
                                : (size_t)2 * NB * CH_um));

    for (int b = tid; b < NB; b += 256) cfrag[b] = C[(s * NB + b) * NCB + bin];
    fhist[tid] = 0;
    __syncthreads();

    // exclusive scan of fragment lengths (2/thread)
    {
        const int a0 = cfrag[2 * tid];
        const int a1 = cfrag[2 * tid + 1];
        const int ss = a0 + a1;
        const int incl = block_scan_incl(ss, tid, wsum);
        const int excl = incl - ss;
        foff[2 * tid] = excl;
        foff[2 * tid + 1] = excl + a0;
        if (tid == 255) foff[NB] = incl;
    }
    __syncthreads();
    const int nbin = foff[NB];
    const int nel = min(nbin, ELCAP);

    // copy fragments -> el (thread per fragment)
    for (int b = tid; b < NB; b += 256) {
        const int c = cfrag[b];
        if (c == 0) continue;
        const int off = LB[(s * NB + b) * NCB + bin];
        const int* frag = preg + (size_t)b * CH + off;
        const int dst0 = foff[b];
        for (int j = 0; j < c; ++j) {
            const int v = frag[j];
            const int idx = dst0 + j;
            if (idx < ELCAP) {
                el[idx] = v;
            } else {
                const int i = atomicAdd(ovf_meta, 1);
                if (i < OVF_MAX) {
                    ovf_list[2 * i]     = (s << 18) | (bin * 256 + (v & 255));
                    ovf_list[2 * i + 1] = v >> 8;
                }
            }
        }
    }
    __syncthreads();

    // fine histogram over dst&255
    for (int i = tid; i < nel; i += 256) atomicAdd(&fhist[el[i] & 255], 1);
    __syncthreads();

    // exclusive scan of fhist; emit rowstart/rowcnt
    {
        const int v = fhist[tid];
        const int incl = block_scan_incl(v, tid, wsum);
        const int excl = incl - v;
        frank[tid] = excl;
        const int r = bin * 256 + tid;
        if (r < NROWS) {
            rowstart_all[s * NROWS + r] = ((s * NCB) + bin) * CAPB + excl;
            rowcnt_all[s * NROWS + r] = v;
        }
    }
    __syncthreads();

    // rank + place into sorted
    for (int i = tid; i < nel; i += 256) {
        const int p = el[i];
        const int pos = atomicAdd(&frank[p & 255], 1);
        sorted[pos] = p >> 8;
    }
    __syncthreads();

    // flush coalesced
    int* outp = csr + ((size_t)s * NCB + bin) * CAPB;
    for (int i = tid; i < nel; i += 256) outp[i] = sorted[i];
}

// ---------------------------------------------------------------------------
// K3: gather-accumulate over CSR. Wave per dst row pair (2 rows in flight,
// 8 outstanding loads), lane = channel.
// ---------------------------------------------------------------------------
__global__ __launch_bounds__(256) void gather_kernel(
    const int* __restrict__ csr,
    const float* __restrict__ x,
    const int* __restrict__ rowcnt,
    const int* __restrict__ rowstart,
    float* __restrict__ outbase,   // row stride 128 floats
    int out_off, int nrows)
{
    const int lane = threadIdx.x & 63;
    const int wid = __builtin_amdgcn_readfirstlane(
        (blockIdx.x * blockDim.x + threadIdx.x) >> 6);
    const int nw = (gridDim.x * blockDim.x) >> 6;
    const int rpw = (nrows + nw - 1) / nw;
    const int r0 = wid * rpw;
    const int r1 = min(r0 + rpw, nrows);

    int r = r0;
    for (; r + 2 <= r1; r += 2) {
        const int cA = rowcnt[r];
        const int cB = rowcnt[r + 1];
        const int baseA = rowstart[r];
        const int baseB = rowstart[r + 1];
        float a0 = 0.f, a1 = 0.f, a2 = 0.f, a3 = 0.f;
        float b0 = 0.f, b1 = 0.f, b2 = 0.f, b3 = 0.f;
        int jA = 0, jB = 0;
        while (jA + 4 <= cA && jB + 4 <= cB) {
            const int sa0 = csr[baseA + jA];
            const int sa1 = csr[baseA + jA + 1];
            const int sa2 = csr[baseA + jA + 2];
            const int sa3 = csr[baseA + jA + 3];
            const int sb0 = csr[baseB + jB];
            const int sb1 = csr[baseB + jB + 1];
            const int sb2 = csr[baseB + jB + 2];
            const int sb3 = csr[baseB + jB + 3];
            a0 += x[(size_t)sa0 * 64 + lane];
            a1 += x[(size_t)sa1 * 64 + lane];
            a2 += x[(size_t)sa2 * 64 + lane];
            a3 += x[(size_t)sa3 * 64 + lane];
            b0 += x[(size_t)sb0 * 64 + lane];
            b1 += x[(size_t)sb1 * 64 + lane];
            b2 += x[(size_t)sb2 * 64 + lane];
            b3 += x[(size_t)sb3 * 64 + lane];
            jA += 4; jB += 4;
        }
        while (jA < cA && jB < cB) {
            const int sa0 = csr[baseA + jA];
            const int sb0 = csr[baseB + jB];
            a0 += x[(size_t)sa0 * 64 + lane];
            b0 += x[(size_t)sb0 * 64 + lane];
            ++jA; ++jB;
        }
        for (; jA + 4 <= cA; jA += 4) {
            const int s0 = csr[baseA + jA];
            const int s1 = csr[baseA + jA + 1];
            const int s2 = csr[baseA + jA + 2];
            const int s3 = csr[baseA + jA + 3];
            a0 += x[(size_t)s0 * 64 + lane];
            a1 += x[(size_t)s1 * 64 + lane];
            a2 += x[(size_t)s2 * 64 + lane];
            a3 += x[(size_t)s3 * 64 + lane];
        }
        for (; jA < cA; ++jA) a0 += x[(size_t)csr[baseA + jA] * 64 + lane];
        for (; jB + 4 <= cB; jB += 4) {
            const int s0 = csr[baseB + jB];
            const int s1 = csr[baseB + jB + 1];
            const int s2 = csr[baseB + jB + 2];
            const int s3 = csr[baseB + jB + 3];
            b0 += x[(size_t)s0 * 64 + lane];
            b1 += x[(size_t)s1 * 64 + lane];
            b2 += x[(size_t)s2 * 64 + lane];
            b3 += x[(size_t)s3 * 64 + lane];
        }
        for (; jB < cB; ++jB) b0 += x[(size_t)csr[baseB + jB] * 64 + lane];

        outbase[(size_t)r * 128 + out_off + lane] = (a0 + a1) + (a2 + a3);
        outbase[(size_t)(r + 1) * 128 + out_off + lane] = (b0 + b1) + (b2 + b3);
    }
    for (; r < r1; ++r) {
        const int c = rowcnt[r];
        const int base = rowstart[r];
        float a0 = 0.f, a1 = 0.f, a2 = 0.f, a3 = 0.f;
        int j = 0;
        for (; j + 4 <= c; j += 4) {
            const int s0 = csr[base + j];
            const int s1 = csr[base + j + 1];
            const int s2 = csr[base + j + 2];
            const int s3 = csr[base + j + 3];
            a0 += x[(size_t)s0 * 64 + lane];
            a1 += x[(size_t)s1 * 64 + lane];
            a2 += x[(size_t)s2 * 64 + lane];
            a3 += x[(size_t)s3 * 64 + lane];
        }
        for (; j < c; ++j) a0 += x[(size_t)csr[base + j] * 64 + lane];
        outbase[(size_t)r * 128 + out_off + lane] = (a0 + a1) + (a2 + a3);
    }
}

// ---------------------------------------------------------------------------
// K4: overflow fixup (statistically empty). Adds x[src] into gathered sums
// and fixes counts, between gathers and finalizes.
// ---------------------------------------------------------------------------
__global__ __launch_bounds__(256) void fixup_kernel(
    const int* __restrict__ ovf_meta,
    const int* __restrict__ ovf_list,
    const float* __restrict__ user_x,
    const float* __restrict__ movie_x,
    const float* __restrict__ entity_x,
    int* __restrict__ rowcnt_all,
    float* __restrict__ out_user,
    float* __restrict__ out_movie)
{
    const int n = min(ovf_meta[0], OVF_MAX);
    const int lane = threadIdx.x & 63;
    const int wv = (blockIdx.x * blockDim.x + threadIdx.x) >> 6;
    const int nw = (gridDim.x * blockDim.x) >> 6;
    for (int i = wv; i < n; i += nw) {
        const int key = ovf_list[2 * i];
        const int src = ovf_list[2 * i + 1];
        const int s = key >> 18;
        const int dst = key & 0x3FFFF;
        if (dst >= NROWS) continue;
        if (s == 0) {
            atomicAdd(&out_user[(size_t)dst * 128 + 64 + lane],
                      user_x[(size_t)src * 64 + lane]);
        } else if (s == 1) {
            atomicAdd(&out_movie[(size_t)dst * 128 + 64 + lane],
                      movie_x[(size_t)src * 64 + lane]);
        } else {
            atomicAdd(&out_movie[(size_t)dst * 128 + lane],
                      entity_x[(size_t)src * 64 + lane]);
        }
        if (lane == 0) atomicAdd(&rowcnt_all[s * NROWS + dst], 1);
    }
}

// ---------------------------------------------------------------------------
// Prep: split W_cat = [W1;W2;Wrel;Wroot] into bf16 hi/lo, pre-swizzled for
// the fragment mapping: frag f=(s*4+t)*64+lane, elem j: k=32s+8*(lane>>4)+j,
// col=16t+(lane&15).
// ---------------------------------------------------------------------------
__global__ __launch_bounds__(256) void bsplit_kernel(
    const float* __restrict__ W1, const float* __restrict__ W2,
    const float* __restrict__ Wrel, const float* __restrict__ Wroot,
    unsigned short* __restrict__ BH, unsigned short* __restrict__ BL)
{
    const int idx = blockIdx.x * blockDim.x + threadIdx.x;
    if (idx >= 8 * 4 * 64 * 8) return;
    const int j = idx & 7;
    const int f = idx >> 3;
    const int l = f & 63;
    const int t = (f >> 6) & 3;
    const int s = f >> 8;
    const int k = 32 * s + 8 * (l >> 4) + j;
    const int col = 16 * t + (l & 15);
    const float* Wsrc;
    switch (k >> 6) {
        case 0:  Wsrc = W1;    break;
        case 1:  Wsrc = W2;    break;
        case 2:  Wsrc = Wrel;  break;
        default: Wsrc = Wroot; break;
    }
    const float v = Wsrc[(k & 63) * 64 + col];
    const unsigned int bits = __float_as_uint(v);
    const unsigned short h = (unsigned short)(bits >> 16);
    const float rem = v - __uint_as_float((unsigned)h << 16);
    BH[idx] = h;
    BL[idx] = (unsigned short)(__float_as_uint(rem) >> 16);
}

// ---- bf16x3 split helpers ----
__device__ __forceinline__ short bf_hi(float v, float& rem) {
    const unsigned int b = __float_as_uint(v);
    const unsigned short h = (unsigned short)(b >> 16);
    rem = v - __uint_as_float((unsigned)h << 16);
    return (short)h;
}
__device__ __forceinline__ short bf_tr(float v) {
    return (short)(__float_as_uint(v) >> 16);
}
__device__ __forceinline__ void split8(float4 q0, float4 q1,
                                       bf16x8& Ah, bf16x8& Al) {
    float r0, r1, r2, r3, r4, r5, r6, r7;
    Ah[0] = bf_hi(q0.x, r0); Ah[1] = bf_hi(q0.y, r1);
    Ah[2] = bf_hi(q0.z, r2); Ah[3] = bf_hi(q0.w, r3);
    Ah[4] = bf_hi(q1.x, r4); Ah[5] = bf_hi(q1.y, r5);
    Ah[6] = bf_hi(q1.z, r6); Ah[7] = bf_hi(q1.w, r7);
    Al[0] = bf_tr(r0); Al[1] = bf_tr(r1); Al[2] = bf_tr(r2); Al[3] = bf_tr(r3);
    Al[4] = bf_tr(r4); Al[5] = bf_tr(r5); Al[6] = bf_tr(r6); Al[7] = bf_tr(r7);
}

#define MFMA3(acc, Ah, Al, Bh, Bl)                                           \
    acc = __builtin_amdgcn_mfma_f32_16x16x32_bf16(Ah, Bh, acc, 0, 0, 0);     \
    acc = __builtin_amdgcn_mfma_f32_16x16x32_bf16(Al, Bh, acc, 0, 0, 0);     \
    acc = __builtin_amdgcn_mfma_f32_16x16x32_bf16(Ah, Bl, acc, 0, 0, 0);

// ---------------------------------------------------------------------------
// Merged MFMA finalize: blocks [0, MBLKS) = movies (K=256), rest = users
// (K=128). Both paths stream each row once (no L3 reuse -> safe to co-run).
// ---------------------------------------------------------------------------
#define MBLKS (NMOVIES / 64)
__global__ __launch_bounds__(256) void finalize_all_mfma(
    const float* __restrict__ user_x,
    const float* __restrict__ movie_x,
    const float* __restrict__ entity_x,
    const int* __restrict__ cnt_u, const int* __restrict__ cnt_m,
    const int* __restrict__ cnt_e,
    const float* __restrict__ b1, const float* __restrict__ b2,
    const float* __restrict__ brgcn,
    const unsigned short* __restrict__ BH,
    const unsigned short* __restrict__ BL,
    float* __restrict__ out_user, float* __restrict__ out_movie)
{
    const int lane = threadIdx.x & 63;
    const int wv = threadIdx.x >> 6;
    const int sub = lane & 15, grp = lane >> 4;

    if (blockIdx.x < MBLKS) {
        // ---------------- movie path ----------------
        const int rbase = blockIdx.x * 64 + wv * 16;
        const int myrow = rbase + sub;
        const float invce = 1.0f / fmaxf((float)cnt_e[myrow], 1.0f);

        f32x4 acc0 = {0.f, 0.f, 0.f, 0.f}, acc1 = acc0, acc2 = acc0, acc3 = acc0;

#pragma unroll
        for (int s = 0; s < 8; ++s) {
            float4 q0, q1;
            if (s < 2) {
                const float* p = out_movie + (size_t)myrow * 128 + 64 + 32 * s + 8 * grp;
                q0 = *(const float4*)p;
                q1 = *(const float4*)(p + 4);
            } else if (s < 4) {
                const int off = 32 * (s - 2) + 8 * grp;
                const float* ps = out_movie + (size_t)myrow * 128 + 64 + off;
                const float* px = movie_x + (size_t)myrow * 64 + off;
                const float4 s0 = *(const float4*)ps, s1 = *(const float4*)(ps + 4);
                const float4 x0 = *(const float4*)px, x1 = *(const float4*)(px + 4);
                q0.x = s0.x * x0.x; q0.y = s0.y * x0.y;
                q0.z = s0.z * x0.z; q0.w = s0.w * x0.w;
                q1.x = s1.x * x1.x; q1.y = s1.y * x1.y;
                q1.z = s1.z * x1.z; q1.w = s1.w * x1.w;
            } else if (s < 6) {
                const float* p = out_movie + (size_t)myrow * 128 + 32 * (s - 4) + 8 * grp;
                const float4 e0 = *(const float4*)p, e1 = *(const float4*)(p + 4);
                q0.x = e0.x * invce; q0.y = e0.y * invce;
                q0.z = e0.z * invce; q0.w = e0.w * invce;
                q1.x = e1.x * invce; q1.y = e1.y * invce;
                q1.z = e1.z * invce; q1.w = e1.w * invce;
            } else {
                const float* p = entity_x + (size_t)myrow * 64 + 32 * (s - 6) + 8 * grp;
                q0 = *(const float4*)p;
                q1 = *(const float4*)(p + 4);
            }
            bf16x8 Ah, Al;
            split8(q0, q1, Ah, Al);
#pragma unroll
            for (int t = 0; t < 4; ++t) {
                const int fo = ((s * 4 + t) * 64 + lane) * 8;
                const bf16x8 Bh = *(const bf16x8*)(BH + fo);
                const bf16x8 Bl = *(const bf16x8*)(BL + fo);
                if (t == 0) { MFMA3(acc0, Ah, Al, Bh, Bl) }
                else if (t == 1) { MFMA3(acc1, Ah, Al, Bh, Bl) }
                else if (t == 2) { MFMA3(acc2, Ah, Al, Bh, Bl) }
                else { MFMA3(acc3, Ah, Al, Bh, Bl) }
            }
        }

#pragma unroll
        for (int i = 0; i < 4; ++i) {
            const int row = rbase + 4 * i + grp;
            const float4 xv = *(const float4*)(movie_x + (size_t)row * 64 + sub * 4);
            *(float4*)(out_movie + (size_t)row * 128 + sub * 4) = xv;
        }

#pragma unroll
        for (int t = 0; t < 4; ++t) {
            const int col = 16 * t + sub;
            const float bb = b1[col] + b2[col];
            const float br = brgcn[col];
            const f32x4 a = (t == 0) ? acc0 : (t == 1) ? acc1 : (t == 2) ? acc2 : acc3;
#pragma unroll
            for (int r = 0; r < 4; ++r) {
                const int row = rbase + 4 * grp + r;
                out_movie[(size_t)row * 128 + 64 + col] =
                    a[r] + (float)cnt_m[row] * bb + br;
            }
        }
    } else {
        // ---------------- user path ----------------
        const int rbase = (blockIdx.x - MBLKS) * 64 + wv * 16;
        const int myrow = rbase + sub;

        f32x4 acc0 = {0.f, 0.f, 0.f, 0.f}, acc1 = acc0, acc2 = acc0, acc3 = acc0;

#pragma unroll
        for (int s = 0; s < 4; ++s) {
            float4 q0, q1;
            if (s < 2) {
                const float* p = out_user + (size_t)myrow * 128 + 64 + 32 * s + 8 * grp;
                q0 = *(const float4*)p;
                q1 = *(const float4*)(p + 4);
            } else {
                const int off = 32 * (s - 2) + 8 * grp;
                const float* ps = out_user + (size_t)myrow * 128 + 64 + off;
                const float* px = user_x + (size_t)myrow * 64 + off;
                const float4 s0 = *(const float4*)ps, s1 = *(const float4*)(ps + 4);
                const float4 x0 = *(const float4*)px, x1 = *(const float4*)(px + 4);
                q0.x = s0.x * x0.x; q0.y = s0.y * x0.y;
                q0.z = s0.z * x0.z; q0.w = s0.w * x0.w;
                q1.x = s1.x * x1.x; q1.y = s1.y * x1.y;
                q1.z = s1.z * x1.z; q1.w = s1.w * x1.w;
            }
            bf16x8 Ah, Al;
            split8(q0, q1, Ah, Al);
#pragma unroll
            for (int t = 0; t < 4; ++t) {
                const int fo = ((s * 4 + t) * 64 + lane) * 8;
                const bf16x8 Bh = *(const bf16x8*)(BH + fo);
                const bf16x8 Bl = *(const bf16x8*)(BL + fo);
                if (t == 0) { MFMA3(acc0, Ah, Al, Bh, Bl) }
                else if (t == 1) { MFMA3(acc1, Ah, Al, Bh, Bl) }
                else if (t == 2) { MFMA3(acc2, Ah, Al, Bh, Bl) }
                else { MFMA3(acc3, Ah, Al, Bh, Bl) }
            }
        }

#pragma unroll
        for (int i = 0; i < 4; ++i) {
            const int row = rbase + 4 * i + grp;
            const float4 xv = *(const float4*)(user_x + (size_t)row * 64 + sub * 4);
            *(float4*)(out_user + (size_t)row * 128 + sub * 4) = xv;
        }

#pragma unroll
        for (int t = 0; t < 4; ++t) {
            const int col = 16 * t + sub;
            const float bb = b1[col] + b2[col];
            const f32x4 a = (t == 0) ? acc0 : (t == 1) ? acc1 : (t == 2) ? acc2 : acc3;
#pragma unroll
            for (int r = 0; r < 4; ++r) {
                const int row = rbase + 4 * grp + r;
                out_user[(size_t)row * 128 + 64 + col] =
                    a[r] + (float)cnt_u[row] * bb;
            }
        }
    }
}

extern "C" void kernel_launch(void* const* d_in, const int* in_sizes, int n_in,
                              void* d_out, int out_size, void* d_ws, size_t ws_size,
                              hipStream_t stream)
{
    const float* user_x   = (const float*)d_in[0];
    const float* movie_x  = (const float*)d_in[1];
    const float* entity_x = (const float*)d_in[2];
    const int*   um       = (const int*)d_in[3];
    const int*   me       = (const int*)d_in[4];
    const float* W1       = (const float*)d_in[5];
    const float* b1       = (const float*)d_in[6];
    const float* W2       = (const float*)d_in[7];
    const float* b2       = (const float*)d_in[8];
    const float* Wrel     = (const float*)d_in[9];
    const float* Wroot    = (const float*)d_in[10];
    const float* brgcn    = (const float*)d_in[11];

    const int E_um = in_sizes[3] / 2;
    const int E_me = in_sizes[4] / 2;
    const int CH_um = (E_um + NB - 1) / NB;
    const int CH_me = (E_me + NB - 1) / NB;

    float* out_user  = (float*)d_out;                         // [NUSERS, 128]
    float* out_movie = out_user + (size_t)NUSERS * 128;       // [NMOVIES, 128]

    // Workspace layout (ints)
    int* C        = (int*)d_ws;                       // [3*NB*NCB]
    int* LB       = C + 3 * NB * NCB;                 // [3*NB*NCB]
    int* rowcnt   = LB + 3 * NB * NCB;                // [3*NROWS]
    int* rowstart = rowcnt + 3 * NROWS;               // [3*NROWS]
    int* ovf_meta = rowstart + 3 * NROWS;             // [2] - zeroed
    int* ovf_list = ovf_meta + 2;                     // [OVF_MAX*2]
    int* part     = ovf_list + 2 * OVF_MAX;           // [2*NB*CH_um + NB*CH_me]
    int* csr      = part + (size_t)2 * NB * CH_um + (size_t)NB * CH_me; // [3*NCB*CAPB]
    uintptr_t bp = (uintptr_t)(csr + (size_t)3 * NCB * CAPB);
    bp = (bp + 63) & ~(uintptr_t)63;
    unsigned short* BH = (unsigned short*)bp;         // [16384]
    unsigned short* BL = BH + 16384;                  // [16384]

    int* cnt_u = rowcnt;
    int* cnt_m = rowcnt + NROWS;
    int* cnt_e = rowcnt + 2 * NROWS;

    hipMemsetAsync(ovf_meta, 0, 2 * sizeof(int), stream);

    bsplit_kernel<<<64, 256, 0, stream>>>(W1, W2, Wrel, Wroot, BH, BL);
    bin_scatter_kernel<<<3 * NB, 256, 0, stream>>>(um, me, C, LB, part,
                                                   E_um, E_me, CH_um, CH_me);
    bin_csr_kernel<<<3 * NCB, 256, 0, stream>>>(part, C, LB, csr,
                                                rowcnt, rowstart,
                                                ovf_meta, ovf_list,
                                                CH_um, CH_me);

    // Gather phases (stream-sequential so each side's x-table stays L3-hot).
    gather_kernel<<<4096, 256, 0, stream>>>(csr, entity_x,
                                            cnt_e, rowstart + 2 * NROWS,
                                            out_movie, 0, NMOVIES);
    gather_kernel<<<4096, 256, 0, stream>>>(csr, movie_x,
                                            cnt_m, rowstart + NROWS,
                                            out_movie, 64, NMOVIES);
    gather_kernel<<<4096, 256, 0, stream>>>(csr, user_x,
                                            cnt_u, rowstart,
                                            out_user, 64, NUSERS);

    fixup_kernel<<<16, 256, 0, stream>>>(ovf_meta, ovf_list, user_x, movie_x,
                                         entity_x, rowcnt, out_user, out_movie);

    finalize_all_mfma<<<MBLKS + NUSERS / 64, 256, 0, stream>>>(
        user_x, movie_x, entity_x, cnt_u, cnt_m, cnt_e,
        b1, b2, brgcn, BH, BL, out_user, out_movie);
}

// Round 17
// 338.950 us; speedup vs baseline: 1.0436x; 1.0436x over previous
//
#include <hip/hip_runtime.h>

#define NUSERS  200000
#define NMOVIES 200000
#define NROWS   200000
#define NCB     782            // coarse bins: key >> 8
#define NB      512            // partition chunks per stream
#define CAPB    1792           // csr capacity per bin
#define ELCAP   1792
#define OVF_MAX 8192

typedef __attribute__((ext_vector_type(8))) short bf16x8;
typedef __attribute__((ext_vector_type(4))) float f32x4;

// ---------------------------------------------------------------------------
// Block-wide inclusive scan over 256 threads: wave shfl scan + cross-wave
// combine. 2 barriers vs 16 for LDS Hillis-Steele.
// ---------------------------------------------------------------------------
__device__ __forceinline__ int block_scan_incl(int v, int tid, int* wsum)
{
#pragma unroll
    for (int off = 1; off < 64; off <<= 1) {
        const int t = __shfl_up(v, off);
        if ((tid & 63) >= off) v += t;
    }
    const int wv = tid >> 6;
    if ((tid & 63) == 63) wsum[wv] = v;
    __syncthreads();
    int add = 0;
    if (wv > 0) add += wsum[0];
    if (wv > 1) add += wsum[1];
    if (wv > 2) add += wsum[2];
    __syncthreads();           // allow wsum reuse by a subsequent scan
    return v + add;
}

// ---------------------------------------------------------------------------
// K1: atomic-free partition. Block (s,blk) bins its chunk by key>>8 in LDS
// and writes it back bin-major + C (counts) + LB (offsets).
// Streams: 0 = um user-side (key=a,val=b); 1 = um movie-side (key=b,val=a);
//          2 = me (key=d, val=s).  part entries: (val<<8)|(key&255).
// ---------------------------------------------------------------------------
__global__ __launch_bounds__(256) void bin_scatter_kernel(
    const int* __restrict__ um, const int* __restrict__ me,
    int* __restrict__ C, int* __restrict__ LB, int* __restrict__ part,
    int E_um, int E_me, int CH_um, int CH_me)
{
    __shared__ int hist[NCB];
    __shared__ int lscan[NCB];
    __shared__ int wsum[4];
    __shared__ int stage[1984];

    const int bid = blockIdx.x;
    const int s = bid / NB;
    const int blk = bid % NB;
    const int E  = (s < 2) ? E_um : E_me;
    const int CH = (s < 2) ? CH_um : CH_me;
    const int t0 = blk * CH;
    const int n = max(0, min(t0 + CH, E) - t0);
    const int tid = threadIdx.x;

    const int* kp;
    const int* vp;
    if (s == 0)      { kp = um;        vp = um + E_um; }
    else if (s == 1) { kp = um + E_um; vp = um; }
    else             { kp = me + E_me; vp = me; }

    for (int i = tid; i < NCB; i += 256) hist[i] = 0;
    __syncthreads();

    for (int j = tid; j < n; j += 256) {
        const int key = kp[t0 + j];
        atomicAdd(&hist[key >> 8], 1);
    }
    __syncthreads();

    const int crow = (s * NB + blk) * NCB;
    for (int i = tid; i < NCB; i += 256) C[crow + i] = hist[i];

    {
        const int b4 = tid * 4;
        const int v0 = (b4 + 0 < NCB) ? hist[b4 + 0] : 0;
        const int v1 = (b4 + 1 < NCB) ? hist[b4 + 1] : 0;
        const int v2 = (b4 + 2 < NCB) ? hist[b4 + 2] : 0;
        const int v3 = (b4 + 3 < NCB) ? hist[b4 + 3] : 0;
        const int ssum = v0 + v1 + v2 + v3;
        const int incl = block_scan_incl(ssum, tid, wsum);
        const int excl = incl - ssum;
        if (b4 + 0 < NCB) lscan[b4 + 0] = excl;
        if (b4 + 1 < NCB) lscan[b4 + 1] = excl + v0;
        if (b4 + 2 < NCB) lscan[b4 + 2] = excl + v0 + v1;
        if (b4 + 3 < NCB) lscan[b4 + 3] = excl + v0 + v1 + v2;
    }
    __syncthreads();

    for (int i = tid; i < NCB; i += 256) LB[crow + i] = lscan[i];
    for (int i = tid; i < NCB; i += 256) hist[i] = lscan[i];
    __syncthreads();

    for (int j = tid; j < n; j += 256) {
        const int key = kp[t0 + j];
        const int val = vp[t0 + j];
        const int pos = atomicAdd(&hist[key >> 8], 1);
        stage[pos] = (val << 8) | (key & 255);
    }
    __syncthreads();

    int* preg;
    if (s == 0)      preg = part + (size_t)blk * CH_um;
    else if (s == 1) preg = part + (size_t)NB * CH_um + (size_t)blk * CH_um;
    else             preg = part + (size_t)2 * NB * CH_um + (size_t)blk * CH_me;
    for (int i = tid; i < n; i += 256) preg[i] = stage[i];
}

// ---------------------------------------------------------------------------
// K2: per-bin CSR builder. Copies the bin's edges from the NB fragments into
// LDS (thread-per-fragment), fine-sorts by dst&255 via LDS hist+scan+rank,
// flushes a contiguous src list + exact rowcnt/rowstart.
// ---------------------------------------------------------------------------
__global__ __launch_bounds__(256) void bin_csr_kernel(
    const int* __restrict__ part,
    const int* __restrict__ C, const int* __restrict__ LB,
    int* __restrict__ csr,            // [3][NCB][CAPB]
    int* __restrict__ rowcnt_all,     // [3][NROWS]
    int* __restrict__ rowstart_all,   // [3][NROWS]
    int* __restrict__ ovf_meta, int* __restrict__ ovf_list,
    int CH_um, int CH_me)
{
    __shared__ int cfrag[NB];
    __shared__ int foff[NB + 1];
    __shared__ int wsum[4];
    __shared__ int el[ELCAP];
    __shared__ int sorted[ELCAP];
    __shared__ int fhist[256];
    __shared__ int frank[256];

    const int bid = blockIdx.x;
    const int s = bid / NCB;
    const int bin = bid % NCB;
    const int tid = threadIdx.x;
    const int CH = (s < 2) ? CH_um : CH_me;
    const int* preg = part + (s == 0 ? (size_t)0
                      : (s == 1 ? (size_t)NB * CH_um
                                : (size_t)2 * NB * CH_um));

    for (int b = tid; b < NB; b += 256) cfrag[b] = C[(s * NB + b) * NCB + bin];
    fhist[tid] = 0;
    __syncthreads();

    // exclusive scan of fragment lengths (2/thread)
    {
        const int a0 = cfrag[2 * tid];
        const int a1 = cfrag[2 * tid + 1];
        const int ss = a0 + a1;
        const int incl = block_scan_incl(ss, tid, wsum);
        const int excl = incl - ss;
        foff[2 * tid] = excl;
        foff[2 * tid + 1] = excl + a0;
        if (tid == 255) foff[NB] = incl;
    }
    __syncthreads();
    const int nbin = foff[NB];
    const int nel = min(nbin, ELCAP);

    // copy fragments -> el (thread per fragment)
    for (int b = tid; b < NB; b += 256) {
        const int c = cfrag[b];
        if (c == 0) continue;
        const int off = LB[(s * NB + b) * NCB + bin];
        const int* frag = preg + (size_t)b * CH + off;
        const int dst0 = foff[b];
        for (int j = 0; j < c; ++j) {
            const int v = frag[j];
            const int idx = dst0 + j;
            if (idx < ELCAP) {
                el[idx] = v;
            } else {
                const int i = atomicAdd(ovf_meta, 1);
                if (i < OVF_MAX) {
                    ovf_list[2 * i]     = (s << 18) | (bin * 256 + (v & 255));
                    ovf_list[2 * i + 1] = v >> 8;
                }
            }
        }
    }
    __syncthreads();

    // fine histogram over dst&255
    for (int i = tid; i < nel; i += 256) atomicAdd(&fhist[el[i] & 255], 1);
    __syncthreads();

    // exclusive scan of fhist; emit rowstart/rowcnt
    {
        const int v = fhist[tid];
        const int incl = block_scan_incl(v, tid, wsum);
        const int excl = incl - v;
        frank[tid] = excl;
        const int r = bin * 256 + tid;
        if (r < NROWS) {
            rowstart_all[s * NROWS + r] = ((s * NCB) + bin) * CAPB + excl;
            rowcnt_all[s * NROWS + r] = v;
        }
    }
    __syncthreads();

    // rank + place into sorted
    for (int i = tid; i < nel; i += 256) {
        const int p = el[i];
        const int pos = atomicAdd(&frank[p & 255], 1);
        sorted[pos] = p >> 8;
    }
    __syncthreads();

    // flush coalesced
    int* outp = csr + ((size_t)s * NCB + bin) * CAPB;
    for (int i = tid; i < nel; i += 256) outp[i] = sorted[i];
}

// ---------------------------------------------------------------------------
// K3: gather-accumulate over CSR. Wave per dst row pair (2 rows in flight,
// 8 outstanding loads), lane = channel.
// ---------------------------------------------------------------------------
__global__ __launch_bounds__(256) void gather_kernel(
    const int* __restrict__ csr,
    const float* __restrict__ x,
    const int* __restrict__ rowcnt,
    const int* __restrict__ rowstart,
    float* __restrict__ outbase,   // row stride 128 floats
    int out_off, int nrows)
{
    const int lane = threadIdx.x & 63;
    const int wid = __builtin_amdgcn_readfirstlane(
        (blockIdx.x * blockDim.x + threadIdx.x) >> 6);
    const int nw = (gridDim.x * blockDim.x) >> 6;
    const int rpw = (nrows + nw - 1) / nw;
    const int r0 = wid * rpw;
    const int r1 = min(r0 + rpw, nrows);

    int r = r0;
    for (; r + 2 <= r1; r += 2) {
        const int cA = rowcnt[r];
        const int cB = rowcnt[r + 1];
        const int baseA = rowstart[r];
        const int baseB = rowstart[r + 1];
        float a0 = 0.f, a1 = 0.f, a2 = 0.f, a3 = 0.f;
        float b0 = 0.f, b1 = 0.f, b2 = 0.f, b3 = 0.f;
        int jA = 0, jB = 0;
        while (jA + 4 <= cA && jB + 4 <= cB) {
            const int sa0 = csr[baseA + jA];
            const int sa1 = csr[baseA + jA + 1];
            const int sa2 = csr[baseA + jA + 2];
            const int sa3 = csr[baseA + jA + 3];
            const int sb0 = csr[baseB + jB];
            const int sb1 = csr[baseB + jB + 1];
            const int sb2 = csr[baseB + jB + 2];
            const int sb3 = csr[baseB + jB + 3];
            a0 += x[(size_t)sa0 * 64 + lane];
            a1 += x[(size_t)sa1 * 64 + lane];
            a2 += x[(size_t)sa2 * 64 + lane];
            a3 += x[(size_t)sa3 * 64 + lane];
            b0 += x[(size_t)sb0 * 64 + lane];
            b1 += x[(size_t)sb1 * 64 + lane];
            b2 += x[(size_t)sb2 * 64 + lane];
            b3 += x[(size_t)sb3 * 64 + lane];
            jA += 4; jB += 4;
        }
        while (jA < cA && jB < cB) {
            const int sa0 = csr[baseA + jA];
            const int sb0 = csr[baseB + jB];
            a0 += x[(size_t)sa0 * 64 + lane];
            b0 += x[(size_t)sb0 * 64 + lane];
            ++jA; ++jB;
        }
        for (; jA + 4 <= cA; jA += 4) {
            const int s0 = csr[baseA + jA];
            const int s1 = csr[baseA + jA + 1];
            const int s2 = csr[baseA + jA + 2];
            const int s3 = csr[baseA + jA + 3];
            a0 += x[(size_t)s0 * 64 + lane];
            a1 += x[(size_t)s1 * 64 + lane];
            a2 += x[(size_t)s2 * 64 + lane];
            a3 += x[(size_t)s3 * 64 + lane];
        }
        for (; jA < cA; ++jA) a0 += x[(size_t)csr[baseA + jA] * 64 + lane];
        for (; jB + 4 <= cB; jB += 4) {
            const int s0 = csr[baseB + jB];
            const int s1 = csr[baseB + jB + 1];
            const int s2 = csr[baseB + jB + 2];
            const int s3 = csr[baseB + jB + 3];
            b0 += x[(size_t)s0 * 64 + lane];
            b1 += x[(size_t)s1 * 64 + lane];
            b2 += x[(size_t)s2 * 64 + lane];
            b3 += x[(size_t)s3 * 64 + lane];
        }
        for (; jB < cB; ++jB) b0 += x[(size_t)csr[baseB + jB] * 64 + lane];

        outbase[(size_t)r * 128 + out_off + lane] = (a0 + a1) + (a2 + a3);
        outbase[(size_t)(r + 1) * 128 + out_off + lane] = (b0 + b1) + (b2 + b3);
    }
    for (; r < r1; ++r) {
        const int c = rowcnt[r];
        const int base = rowstart[r];
        float a0 = 0.f, a1 = 0.f, a2 = 0.f, a3 = 0.f;
        int j = 0;
        for (; j + 4 <= c; j += 4) {
            const int s0 = csr[base + j];
            const int s1 = csr[base + j + 1];
            const int s2 = csr[base + j + 2];
            const int s3 = csr[base + j + 3];
            a0 += x[(size_t)s0 * 64 + lane];
            a1 += x[(size_t)s1 * 64 + lane];
            a2 += x[(size_t)s2 * 64 + lane];
            a3 += x[(size_t)s3 * 64 + lane];
        }
        for (; j < c; ++j) a0 += x[(size_t)csr[base + j] * 64 + lane];
        outbase[(size_t)r * 128 + out_off + lane] = (a0 + a1) + (a2 + a3);
    }
}

// ---------------------------------------------------------------------------
// K4: overflow fixup (statistically empty). Adds x[src] into gathered sums
// and fixes counts, between gathers and finalizes.
// ---------------------------------------------------------------------------
__global__ __launch_bounds__(256) void fixup_kernel(
    const int* __restrict__ ovf_meta,
    const int* __restrict__ ovf_list,
    const float* __restrict__ user_x,
    const float* __restrict__ movie_x,
    const float* __restrict__ entity_x,
    int* __restrict__ rowcnt_all,
    float* __restrict__ out_user,
    float* __restrict__ out_movie)
{
    const int n = min(ovf_meta[0], OVF_MAX);
    const int lane = threadIdx.x & 63;
    const int wv = (blockIdx.x * blockDim.x + threadIdx.x) >> 6;
    const int nw = (gridDim.x * blockDim.x) >> 6;
    for (int i = wv; i < n; i += nw) {
        const int key = ovf_list[2 * i];
        const int src = ovf_list[2 * i + 1];
        const int s = key >> 18;
        const int dst = key & 0x3FFFF;
        if (dst >= NROWS) continue;
        if (s == 0) {
            atomicAdd(&out_user[(size_t)dst * 128 + 64 + lane],
                      user_x[(size_t)src * 64 + lane]);
        } else if (s == 1) {
            atomicAdd(&out_movie[(size_t)dst * 128 + 64 + lane],
                      movie_x[(size_t)src * 64 + lane]);
        } else {
            atomicAdd(&out_movie[(size_t)dst * 128 + lane],
                      entity_x[(size_t)src * 64 + lane]);
        }
        if (lane == 0) atomicAdd(&rowcnt_all[s * NROWS + dst], 1);
    }
}

// ---------------------------------------------------------------------------
// Prep: split W_cat = [W1;W2;Wrel;Wroot] into bf16 hi/lo, pre-swizzled for
// the fragment mapping: frag f=(s*4+t)*64+lane, elem j: k=32s+8*(lane>>4)+j,
// col=16t+(lane&15).
// ---------------------------------------------------------------------------
__global__ __launch_bounds__(256) void bsplit_kernel(
    const float* __restrict__ W1, const float* __restrict__ W2,
    const float* __restrict__ Wrel, const float* __restrict__ Wroot,
    unsigned short* __restrict__ BH, unsigned short* __restrict__ BL)
{
    const int idx = blockIdx.x * blockDim.x + threadIdx.x;
    if (idx >= 8 * 4 * 64 * 8) return;
    const int j = idx & 7;
    const int f = idx >> 3;
    const int l = f & 63;
    const int t = (f >> 6) & 3;
    const int s = f >> 8;
    const int k = 32 * s + 8 * (l >> 4) + j;
    const int col = 16 * t + (l & 15);
    const float* Wsrc;
    switch (k >> 6) {
        case 0:  Wsrc = W1;    break;
        case 1:  Wsrc = W2;    break;
        case 2:  Wsrc = Wrel;  break;
        default: Wsrc = Wroot; break;
    }
    const float v = Wsrc[(k & 63) * 64 + col];
    const unsigned int bits = __float_as_uint(v);
    const unsigned short h = (unsigned short)(bits >> 16);
    const float rem = v - __uint_as_float((unsigned)h << 16);
    BH[idx] = h;
    BL[idx] = (unsigned short)(__float_as_uint(rem) >> 16);
}

// ---- bf16x3 split helpers ----
__device__ __forceinline__ short bf_hi(float v, float& rem) {
    const unsigned int b = __float_as_uint(v);
    const unsigned short h = (unsigned short)(b >> 16);
    rem = v - __uint_as_float((unsigned)h << 16);
    return (short)h;
}
__device__ __forceinline__ short bf_tr(float v) {
    return (short)(__float_as_uint(v) >> 16);
}
__device__ __forceinline__ void split8(float4 q0, float4 q1,
                                       bf16x8& Ah, bf16x8& Al) {
    float r0, r1, r2, r3, r4, r5, r6, r7;
    Ah[0] = bf_hi(q0.x, r0); Ah[1] = bf_hi(q0.y, r1);
    Ah[2] = bf_hi(q0.z, r2); Ah[3] = bf_hi(q0.w, r3);
    Ah[4] = bf_hi(q1.x, r4); Ah[5] = bf_hi(q1.y, r5);
    Ah[6] = bf_hi(q1.z, r6); Ah[7] = bf_hi(q1.w, r7);
    Al[0] = bf_tr(r0); Al[1] = bf_tr(r1); Al[2] = bf_tr(r2); Al[3] = bf_tr(r3);
    Al[4] = bf_tr(r4); Al[5] = bf_tr(r5); Al[6] = bf_tr(r6); Al[7] = bf_tr(r7);
}

#define MFMA3(acc, Ah, Al, Bh, Bl)                                           \
    acc = __builtin_amdgcn_mfma_f32_16x16x32_bf16(Ah, Bh, acc, 0, 0, 0);     \
    acc = __builtin_amdgcn_mfma_f32_16x16x32_bf16(Al, Bh, acc, 0, 0, 0);     \
    acc = __builtin_amdgcn_mfma_f32_16x16x32_bf16(Ah, Bl, acc, 0, 0, 0);

// ---------------------------------------------------------------------------
// Finalize users via MFMA. Block = 4 waves, 64 rows; wave = 16 rows.
// ---------------------------------------------------------------------------
__global__ __launch_bounds__(256) void finalize_user_mfma(
    const float* __restrict__ user_x,
    const int* __restrict__ cnt_u,
    const float* __restrict__ b1, const float* __restrict__ b2,
    const unsigned short* __restrict__ BH,
    const unsigned short* __restrict__ BL,
    float* out_user)
{
    const int lane = threadIdx.x & 63;
    const int wv = threadIdx.x >> 6;
    const int sub = lane & 15, grp = lane >> 4;
    const int rbase = blockIdx.x * 64 + wv * 16;
    const int myrow = rbase + sub;

    f32x4 acc0 = {0.f, 0.f, 0.f, 0.f}, acc1 = acc0, acc2 = acc0, acc3 = acc0;

#pragma unroll
    for (int s = 0; s < 4; ++s) {
        float4 q0, q1;
        if (s < 2) {
            const float* p = out_user + (size_t)myrow * 128 + 64 + 32 * s + 8 * grp;
            q0 = *(const float4*)p;
            q1 = *(const float4*)(p + 4);
        } else {
            const int off = 32 * (s - 2) + 8 * grp;
            const float* ps = out_user + (size_t)myrow * 128 + 64 + off;
            const float* px = user_x + (size_t)myrow * 64 + off;
            const float4 s0 = *(const float4*)ps, s1 = *(const float4*)(ps + 4);
            const float4 x0 = *(const float4*)px, x1 = *(const float4*)(px + 4);
            q0.x = s0.x * x0.x; q0.y = s0.y * x0.y;
            q0.z = s0.z * x0.z; q0.w = s0.w * x0.w;
            q1.x = s1.x * x1.x; q1.y = s1.y * x1.y;
            q1.z = s1.z * x1.z; q1.w = s1.w * x1.w;
        }
        bf16x8 Ah, Al;
        split8(q0, q1, Ah, Al);
#pragma unroll
        for (int t = 0; t < 4; ++t) {
            const int fo = ((s * 4 + t) * 64 + lane) * 8;
            const bf16x8 Bh = *(const bf16x8*)(BH + fo);
            const bf16x8 Bl = *(const bf16x8*)(BL + fo);
            if (t == 0) { MFMA3(acc0, Ah, Al, Bh, Bl) }
            else if (t == 1) { MFMA3(acc1, Ah, Al, Bh, Bl) }
            else if (t == 2) { MFMA3(acc2, Ah, Al, Bh, Bl) }
            else { MFMA3(acc3, Ah, Al, Bh, Bl) }
        }
    }

#pragma unroll
    for (int i = 0; i < 4; ++i) {
        const int row = rbase + 4 * i + grp;
        const float4 xv = *(const float4*)(user_x + (size_t)row * 64 + sub * 4);
        *(float4*)(out_user + (size_t)row * 128 + sub * 4) = xv;
    }

#pragma unroll
    for (int t = 0; t < 4; ++t) {
        const int col = 16 * t + sub;
        const float bb = b1[col] + b2[col];
        const f32x4 a = (t == 0) ? acc0 : (t == 1) ? acc1 : (t == 2) ? acc2 : acc3;
#pragma unroll
        for (int r = 0; r < 4; ++r) {
            const int row = rbase + 4 * grp + r;
            out_user[(size_t)row * 128 + 64 + col] =
                a[r] + (float)cnt_u[row] * bb;
        }
    }
}

// ---------------------------------------------------------------------------
// Finalize movies via MFMA. K=256: [S1, x.S1, Se/ce, ex] @ [W1;W2;Wrel;Wroot]
// ---------------------------------------------------------------------------
__global__ __launch_bounds__(256) void finalize_movie_mfma(
    const float* __restrict__ movie_x,
    const float* __restrict__ entity_x,
    const int* __restrict__ cnt_m, const int* __restrict__ cnt_e,
    const float* __restrict__ b1, const float* __restrict__ b2,
    const float* __restrict__ brgcn,
    const unsigned short* __restrict__ BH,
    const unsigned short* __restrict__ BL,
    float* out_movie)
{
    const int lane = threadIdx.x & 63;
    const int wv = threadIdx.x >> 6;
    const int sub = lane & 15, grp = lane >> 4;
    const int rbase = blockIdx.x * 64 + wv * 16;
    const int myrow = rbase + sub;
    const float invce = 1.0f / fmaxf((float)cnt_e[myrow], 1.0f);

    f32x4 acc0 = {0.f, 0.f, 0.f, 0.f}, acc1 = acc0, acc2 = acc0, acc3 = acc0;

#pragma unroll
    for (int s = 0; s < 8; ++s) {
        float4 q0, q1;
        if (s < 2) {
            const float* p = out_movie + (size_t)myrow * 128 + 64 + 32 * s + 8 * grp;
            q0 = *(const float4*)p;
            q1 = *(const float4*)(p + 4);
        } else if (s < 4) {
            const int off = 32 * (s - 2) + 8 * grp;
            const float* ps = out_movie + (size_t)myrow * 128 + 64 + off;
            const float* px = movie_x + (size_t)myrow * 64 + off;
            const float4 s0 = *(const float4*)ps, s1 = *(const float4*)(ps + 4);
            const float4 x0 = *(const float4*)px, x1 = *(const float4*)(px + 4);
            q0.x = s0.x * x0.x; q0.y = s0.y * x0.y;
            q0.z = s0.z * x0.z; q0.w = s0.w * x0.w;
            q1.x = s1.x * x1.x; q1.y = s1.y * x1.y;
            q1.z = s1.z * x1.z; q1.w = s1.w * x1.w;
        } else if (s < 6) {
            const float* p = out_movie + (size_t)myrow * 128 + 32 * (s - 4) + 8 * grp;
            const float4 e0 = *(const float4*)p, e1 = *(const float4*)(p + 4);
            q0.x = e0.x * invce; q0.y = e0.y * invce;
            q0.z = e0.z * invce; q0.w = e0.w * invce;
            q1.x = e1.x * invce; q1.y = e1.y * invce;
            q1.z = e1.z * invce; q1.w = e1.w * invce;
        } else {
            const float* p = entity_x + (size_t)myrow * 64 + 32 * (s - 6) + 8 * grp;
            q0 = *(const float4*)p;
            q1 = *(const float4*)(p + 4);
        }
        bf16x8 Ah, Al;
        split8(q0, q1, Ah, Al);
#pragma unroll
        for (int t = 0; t < 4; ++t) {
            const int fo = ((s * 4 + t) * 64 + lane) * 8;
            const bf16x8 Bh = *(const bf16x8*)(BH + fo);
            const bf16x8 Bl = *(const bf16x8*)(BL + fo);
            if (t == 0) { MFMA3(acc0, Ah, Al, Bh, Bl) }
            else if (t == 1) { MFMA3(acc1, Ah, Al, Bh, Bl) }
            else if (t == 2) { MFMA3(acc2, Ah, Al, Bh, Bl) }
            else { MFMA3(acc3, Ah, Al, Bh, Bl) }
        }
    }

#pragma unroll
    for (int i = 0; i < 4; ++i) {
        const int row = rbase + 4 * i + grp;
        const float4 xv = *(const float4*)(movie_x + (size_t)row * 64 + sub * 4);
        *(float4*)(out_movie + (size_t)row * 128 + sub * 4) = xv;
    }

#pragma unroll
    for (int t = 0; t < 4; ++t) {
        const int col = 16 * t + sub;
        const float bb = b1[col] + b2[col];
        const float br = brgcn[col];
        const f32x4 a = (t == 0) ? acc0 : (t == 1) ? acc1 : (t == 2) ? acc2 : acc3;
#pragma unroll
        for (int r = 0; r < 4; ++r) {
            const int row = rbase + 4 * grp + r;
            out_movie[(size_t)row * 128 + 64 + col] =
                a[r] + (float)cnt_m[row] * bb + br;
        }
    }
}

extern "C" void kernel_launch(void* const* d_in, const int* in_sizes, int n_in,
                              void* d_out, int out_size, void* d_ws, size_t ws_size,
                              hipStream_t stream)
{
    const float* user_x   = (const float*)d_in[0];
    const float* movie_x  = (const float*)d_in[1];
    const float* entity_x = (const float*)d_in[2];
    const int*   um       = (const int*)d_in[3];
    const int*   me       = (const int*)d_in[4];
    const float* W1       = (const float*)d_in[5];
    const float* b1       = (const float*)d_in[6];
    const float* W2       = (const float*)d_in[7];
    const float* b2       = (const float*)d_in[8];
    const float* Wrel     = (const float*)d_in[9];
    const float* Wroot    = (const float*)d_in[10];
    const float* brgcn    = (const float*)d_in[11];

    const int E_um = in_sizes[3] / 2;
    const int E_me = in_sizes[4] / 2;
    const int CH_um = (E_um + NB - 1) / NB;
    const int CH_me = (E_me + NB - 1) / NB;

    float* out_user  = (float*)d_out;                         // [NUSERS, 128]
    float* out_movie = out_user + (size_t)NUSERS * 128;       // [NMOVIES, 128]

    // Workspace layout (ints)
    int* C        = (int*)d_ws;                       // [3*NB*NCB]
    int* LB       = C + 3 * NB * NCB;                 // [3*NB*NCB]
    int* rowcnt   = LB + 3 * NB * NCB;                // [3*NROWS]
    int* rowstart = rowcnt + 3 * NROWS;               // [3*NROWS]
    int* ovf_meta = rowstart + 3 * NROWS;             // [2] - zeroed
    int* ovf_list = ovf_meta + 2;                     // [OVF_MAX*2]
    int* part     = ovf_list + 2 * OVF_MAX;           // [2*NB*CH_um + NB*CH_me]
    int* csr      = part + (size_t)2 * NB * CH_um + (size_t)NB * CH_me; // [3*NCB*CAPB]
    uintptr_t bp = (uintptr_t)(csr + (size_t)3 * NCB * CAPB);
    bp = (bp + 63) & ~(uintptr_t)63;
    unsigned short* BH = (unsigned short*)bp;         // [16384]
    unsigned short* BL = BH + 16384;                  // [16384]

    int* cnt_u = rowcnt;
    int* cnt_m = rowcnt + NROWS;
    int* cnt_e = rowcnt + 2 * NROWS;

    hipMemsetAsync(ovf_meta, 0, 2 * sizeof(int), stream);

    bsplit_kernel<<<64, 256, 0, stream>>>(W1, W2, Wrel, Wroot, BH, BL);
    bin_scatter_kernel<<<3 * NB, 256, 0, stream>>>(um, me, C, LB, part,
                                                   E_um, E_me, CH_um, CH_me);
    bin_csr_kernel<<<3 * NCB, 256, 0, stream>>>(part, C, LB, csr,
                                                rowcnt, rowstart,
                                                ovf_meta, ovf_list,
                                                CH_um, CH_me);

    // Gather phases (stream-sequential so each side's x-table stays L3-hot).
    gather_kernel<<<4096, 256, 0, stream>>>(csr, entity_x,
                                            cnt_e, rowstart + 2 * NROWS,
                                            out_movie, 0, NMOVIES);
    gather_kernel<<<4096, 256, 0, stream>>>(csr, movie_x,
                                            cnt_m, rowstart + NROWS,
                                            out_movie, 64, NMOVIES);
    gather_kernel<<<4096, 256, 0, stream>>>(csr, user_x,
                                            cnt_u, rowstart,
                                            out_user, 64, NUSERS);

    fixup_kernel<<<16, 256, 0, stream>>>(ovf_meta, ovf_list, user_x, movie_x,
                                         entity_x, rowcnt, out_user, out_movie);

    finalize_user_mfma<<<NUSERS / 64, 256, 0, stream>>>(
        user_x, cnt_u, b1, b2, BH, BL, out_user);
    finalize_movie_mfma<<<NMOVIES / 64, 256, 0, stream>>>(
        movie_x, entity_x, cnt_m, cnt_e, b1, b2, brgcn, BH, BL, out_movie);
}